// Round 6
// baseline (122.769 us; speedup 1.0000x reference)
//
#include <hip/hip_runtime.h>

#define M_VOX   100000
#define N_VOX   200000
#define K_VOL   27
#define C_IN    32
#define C_OUT   64

#define STG0        14                 // offsets in LDS stage 0
#define STG1        (K_VOL - STG0)     // 13 offsets in stage 1
#define BLK_THREADS 1024               // 16 waves; 256 voxels per block
#define VOX_PER_BLK 256
#define BURST       7                  // gather batch: loads issued before uses

typedef __bf16 bf16x8 __attribute__((ext_vector_type(8)));
typedef float  floatx4 __attribute__((ext_vector_type(4)));

// ---- d_ws layout ----
// featsB : (N_VOX+1) rows x 32 bf16 (64 B/row), row N_VOX all-zero
// Bfrag  : 27 * 256 * 16 B bf16 weights in MFMA fragment order
#define FEATSB_BYTES  ((N_VOX + 1) * C_IN * 2)
#define BFRAG_OFF     FEATSB_BYTES

// ---------- fused prep: feats fp32->bf16 (+zero row) | weights->frag ----------
#define FEAT_CHUNKS   ((N_VOX + 1) * 4)
#define FEAT_BLOCKS   ((FEAT_CHUNKS + 255) / 256)
__global__ __launch_bounds__(256) void prep_all(
    const float* __restrict__ feats, const float* __restrict__ kernelw,
    __bf16* __restrict__ featsB, bf16x8* __restrict__ Bfrag)
{
    if (blockIdx.x < FEAT_BLOCKS) {
        const int c = blockIdx.x * 256 + threadIdx.x;
        if (c >= FEAT_CHUNKS) return;
        bf16x8 v;
        if (c < N_VOX * 4) {
            floatx4 f0 = *(const floatx4*)(feats + c * 8);
            floatx4 f1 = *(const floatx4*)(feats + c * 8 + 4);
#pragma unroll
            for (int j = 0; j < 4; ++j) { v[j] = (__bf16)f0[j]; v[4 + j] = (__bf16)f1[j]; }
        } else {
#pragma unroll
            for (int j = 0; j < 8; ++j) v[j] = (__bf16)0.0f;
        }
        *(bf16x8*)(featsB + c * 8) = v;
    } else {
        // weight frag: block k, thread tid -> slot (tile=tid>>6, lane=tid&63)
        // element j = kernel[k][((lane>>4)&3)*8 + j][tile*16 + (lane&15)]
        const int k    = blockIdx.x - FEAT_BLOCKS;
        const int tid  = threadIdx.x;
        const int tile = tid >> 6;
        const int col  = tid & 15;
        const int quad = (tid >> 4) & 3;
        const float* kp = kernelw + k * C_IN * C_OUT + quad * 8 * C_OUT + tile * 16 + col;
        bf16x8 b;
#pragma unroll
        for (int j = 0; j < 8; ++j) b[j] = (__bf16)kp[j * C_OUT];
        Bfrag[k * 256 + tid] = b;
    }
}

// ---------- main ----------
// r4 shell (proven correct): 1024 threads = 16 waves, wave = 16 voxels x 64
// out-channels, B-frags in LDS (stages of 14 + 13 offsets, 57,344 B).
// r6 change: gathers issued in bursts of 7 — all loads of a batch precede
// all uses (compiler cannot sink a load past its use), so per-wave gather
// MLP is 7 (vs ~1 in r4). Register budget kept ~100 VGPR: no launch_bounds
// min-waves clamp, no spill (the r5 failure mode).
// A-frag (16x16x32 bf16): A[m=lane&15][k=(lane>>4)*8+j]
// C/D: col=lane&15 (channel in tile), row=(lane>>4)*4+reg (voxel).
__global__ __launch_bounds__(BLK_THREADS) void sparse_conv_mfma(
    const __bf16* __restrict__ featsB,
    const bf16x8* __restrict__ BfragG,
    const int* __restrict__ in_idx,
    const int* __restrict__ mask,
    float* __restrict__ out)
{
    __shared__ bf16x8 ldsB[STG0 * 256];   // 57,344 B

    const int tid  = threadIdx.x;
    const int lane = tid & 63;
    const int wv   = tid >> 6;
    const int col  = lane & 15;
    const int quad = lane >> 4;

    const int m0 = blockIdx.x * VOX_PER_BLK + wv * 16;
    const bool active = (m0 < M_VOX);   // M_VOX%16==0: waves all-or-nothing

    // stage offsets 0..13 into LDS (all waves participate — barrier safety)
#pragma unroll
    for (int i = tid; i < STG0 * 256; i += BLK_THREADS) ldsB[i] = BfragG[i];

    // full index chain up front: 54 coalesced loads, mask fused -> zero row
    int mi[K_VOL];
    if (active) {
#pragma unroll
        for (int k = 0; k < K_VOL; ++k) {
            const int ix = in_idx[k * M_VOX + m0 + col];
            const int mk = mask[k * M_VOX + m0 + col];
            mi[k] = mk ? ix : N_VOX;
        }
    }
    __syncthreads();   // LDS stage 0 ready

    floatx4 acc0 = {0.f,0.f,0.f,0.f}, acc1 = {0.f,0.f,0.f,0.f};
    floatx4 acc2 = {0.f,0.f,0.f,0.f}, acc3 = {0.f,0.f,0.f,0.f};
    const bf16x8* lbase = ldsB + lane;
    const __bf16* fbase = featsB + quad * 8;

    bf16x8 A[BURST];

    if (active) {
        // ---- stage 0, batch 0: offsets 0..6 ----
#pragma unroll
        for (int j = 0; j < BURST; ++j)
            A[j] = *(const bf16x8*)(fbase + (size_t)mi[j] * C_IN);
#pragma unroll
        for (int j = 0; j < BURST; ++j) {
            const int k = j;
            bf16x8 b0 = lbase[k * 256 + 0 * 64];
            bf16x8 b1 = lbase[k * 256 + 1 * 64];
            bf16x8 b2 = lbase[k * 256 + 2 * 64];
            bf16x8 b3 = lbase[k * 256 + 3 * 64];
            acc0 = __builtin_amdgcn_mfma_f32_16x16x32_bf16(A[j], b0, acc0, 0, 0, 0);
            acc1 = __builtin_amdgcn_mfma_f32_16x16x32_bf16(A[j], b1, acc1, 0, 0, 0);
            acc2 = __builtin_amdgcn_mfma_f32_16x16x32_bf16(A[j], b2, acc2, 0, 0, 0);
            acc3 = __builtin_amdgcn_mfma_f32_16x16x32_bf16(A[j], b3, acc3, 0, 0, 0);
        }
        // ---- stage 0, batch 1: offsets 7..13 ----
#pragma unroll
        for (int j = 0; j < BURST; ++j)
            A[j] = *(const bf16x8*)(fbase + (size_t)mi[BURST + j] * C_IN);
#pragma unroll
        for (int j = 0; j < BURST; ++j) {
            const int k = BURST + j;
            bf16x8 b0 = lbase[k * 256 + 0 * 64];
            bf16x8 b1 = lbase[k * 256 + 1 * 64];
            bf16x8 b2 = lbase[k * 256 + 2 * 64];
            bf16x8 b3 = lbase[k * 256 + 3 * 64];
            acc0 = __builtin_amdgcn_mfma_f32_16x16x32_bf16(A[j], b0, acc0, 0, 0, 0);
            acc1 = __builtin_amdgcn_mfma_f32_16x16x32_bf16(A[j], b1, acc1, 0, 0, 0);
            acc2 = __builtin_amdgcn_mfma_f32_16x16x32_bf16(A[j], b2, acc2, 0, 0, 0);
            acc3 = __builtin_amdgcn_mfma_f32_16x16x32_bf16(A[j], b3, acc3, 0, 0, 0);
        }
    }

    // ---- restage LDS with offsets 14..26 ----
    __syncthreads();   // everyone done reading LDS stage 0
#pragma unroll
    for (int i = tid; i < STG1 * 256; i += BLK_THREADS)
        ldsB[i] = BfragG[STG0 * 256 + i];
    __syncthreads();   // LDS stage 1 ready

    if (active) {
        // ---- stage 1, batch 0: offsets 14..20 ----
#pragma unroll
        for (int j = 0; j < BURST; ++j)
            A[j] = *(const bf16x8*)(fbase + (size_t)mi[STG0 + j] * C_IN);
#pragma unroll
        for (int j = 0; j < BURST; ++j) {
            const int k = j;
            bf16x8 b0 = lbase[k * 256 + 0 * 64];
            bf16x8 b1 = lbase[k * 256 + 1 * 64];
            bf16x8 b2 = lbase[k * 256 + 2 * 64];
            bf16x8 b3 = lbase[k * 256 + 3 * 64];
            acc0 = __builtin_amdgcn_mfma_f32_16x16x32_bf16(A[j], b0, acc0, 0, 0, 0);
            acc1 = __builtin_amdgcn_mfma_f32_16x16x32_bf16(A[j], b1, acc1, 0, 0, 0);
            acc2 = __builtin_amdgcn_mfma_f32_16x16x32_bf16(A[j], b2, acc2, 0, 0, 0);
            acc3 = __builtin_amdgcn_mfma_f32_16x16x32_bf16(A[j], b3, acc3, 0, 0, 0);
        }
        // ---- stage 1, batch 1: offsets 21..26 (6 iters) ----
#pragma unroll
        for (int j = 0; j < STG1 - BURST; ++j)
            A[j] = *(const bf16x8*)(fbase + (size_t)mi[STG0 + BURST + j] * C_IN);
#pragma unroll
        for (int j = 0; j < STG1 - BURST; ++j) {
            const int k = BURST + j;
            bf16x8 b0 = lbase[k * 256 + 0 * 64];
            bf16x8 b1 = lbase[k * 256 + 1 * 64];
            bf16x8 b2 = lbase[k * 256 + 2 * 64];
            bf16x8 b3 = lbase[k * 256 + 3 * 64];
            acc0 = __builtin_amdgcn_mfma_f32_16x16x32_bf16(A[j], b0, acc0, 0, 0, 0);
            acc1 = __builtin_amdgcn_mfma_f32_16x16x32_bf16(A[j], b1, acc1, 0, 0, 0);
            acc2 = __builtin_amdgcn_mfma_f32_16x16x32_bf16(A[j], b2, acc2, 0, 0, 0);
            acc3 = __builtin_amdgcn_mfma_f32_16x16x32_bf16(A[j], b3, acc3, 0, 0, 0);
        }

        float* op = out + (size_t)(m0 + quad * 4) * C_OUT + col;
#pragma unroll
        for (int r = 0; r < 4; ++r) {
            op[r * C_OUT + 0]  = acc0[r];
            op[r * C_OUT + 16] = acc1[r];
            op[r * C_OUT + 32] = acc2[r];
            op[r * C_OUT + 48] = acc3[r];
        }
    }
}

extern "C" void kernel_launch(void* const* d_in, const int* in_sizes, int n_in,
                              void* d_out, int out_size, void* d_ws, size_t ws_size,
                              hipStream_t stream) {
    const float* feats   = (const float*)d_in[0];
    const float* kernelw = (const float*)d_in[1];
    const int*   in_idx  = (const int*)d_in[2];
    const int*   maskp   = (const int*)d_in[3];
    float*       out     = (float*)d_out;

    __bf16* featsB = (__bf16*)d_ws;
    bf16x8* BfragP = (bf16x8*)((char*)d_ws + BFRAG_OFF);

    prep_all<<<dim3(FEAT_BLOCKS + K_VOL), dim3(256), 0, stream>>>(
        feats, kernelw, featsB, BfragP);

    const int blocks = (M_VOX + VOX_PER_BLK - 1) / VOX_PER_BLK;   // 391
    sparse_conv_mfma<<<dim3(blocks), dim3(BLK_THREADS), 0, stream>>>(
        featsB, BfragP, in_idx, maskp, out);
}

// Round 7
// 121.554 us; speedup vs baseline: 1.0100x; 1.0100x over previous
//
#include <hip/hip_runtime.h>

#define M_VOX   100000
#define N_VOX   200000
#define K_VOL   27
#define C_IN    32
#define C_OUT   64

#define STG0        14                 // offsets in LDS stage 0
#define STG1        (K_VOL - STG0)     // 13 offsets in stage 1
#define BLK_THREADS 512                // 8 waves; 128 voxels per block
#define VOX_PER_BLK 128
#define BURST       7                  // gather batch: loads issued before uses

typedef __bf16 bf16x8 __attribute__((ext_vector_type(8)));
typedef float  floatx4 __attribute__((ext_vector_type(4)));

// ---- d_ws layout ----
// featsB : (N_VOX+1) rows x 32 bf16 (64 B/row), row N_VOX all-zero
// Bfrag  : 27 * 256 * 16 B bf16 weights in MFMA fragment order
#define FEATSB_BYTES  ((N_VOX + 1) * C_IN * 2)
#define BFRAG_OFF     FEATSB_BYTES

// ---------- fused prep: feats fp32->bf16 (+zero row) | weights->frag ----------
#define FEAT_CHUNKS   ((N_VOX + 1) * 4)
#define FEAT_BLOCKS   ((FEAT_CHUNKS + 255) / 256)
__global__ __launch_bounds__(256) void prep_all(
    const float* __restrict__ feats, const float* __restrict__ kernelw,
    __bf16* __restrict__ featsB, bf16x8* __restrict__ Bfrag)
{
    if (blockIdx.x < FEAT_BLOCKS) {
        const int c = blockIdx.x * 256 + threadIdx.x;
        if (c >= FEAT_CHUNKS) return;
        bf16x8 v;
        if (c < N_VOX * 4) {
            floatx4 f0 = *(const floatx4*)(feats + c * 8);
            floatx4 f1 = *(const floatx4*)(feats + c * 8 + 4);
#pragma unroll
            for (int j = 0; j < 4; ++j) { v[j] = (__bf16)f0[j]; v[4 + j] = (__bf16)f1[j]; }
        } else {
#pragma unroll
            for (int j = 0; j < 8; ++j) v[j] = (__bf16)0.0f;
        }
        *(bf16x8*)(featsB + c * 8) = v;
    } else {
        // weight frag: block k, thread tid -> slot (tile=tid>>6, lane=tid&63)
        // element j = kernel[k][((lane>>4)&3)*8 + j][tile*16 + (lane&15)]
        const int k    = blockIdx.x - FEAT_BLOCKS;
        const int tid  = threadIdx.x;
        const int tile = tid >> 6;
        const int col  = tid & 15;
        const int quad = (tid >> 4) & 3;
        const float* kp = kernelw + k * C_IN * C_OUT + quad * 8 * C_OUT + tile * 16 + col;
        bf16x8 b;
#pragma unroll
        for (int j = 0; j < 8; ++j) b[j] = (__bf16)kp[j * C_OUT];
        Bfrag[k * 256 + tid] = b;
    }
}

// ---------- main ----------
// r6 wave structure, 512-thread blocks for 2-blocks/CU residency:
//   LDS 57,344 B -> 2 blocks/CU; ~100 VGPR -> 16 waves/CU. One block's
//   barrier/restage/startup phases overlap the other block's compute, and
//   782 blocks / 256 CU at 2-deep residency cuts the 1.53x -> ~1.2x tail.
// Wave = 16 voxels x 64 out-channels; B-frags staged in LDS (14+13 offsets).
// Gathers issued in bursts of 7 (loads precede uses -> MLP 7/wave).
// A-frag (16x16x32 bf16): A[m=lane&15][k=(lane>>4)*8+j]
// C/D: col=lane&15 (channel in tile), row=(lane>>4)*4+reg (voxel).
__global__ __launch_bounds__(BLK_THREADS) void sparse_conv_mfma(
    const __bf16* __restrict__ featsB,
    const bf16x8* __restrict__ BfragG,
    const int* __restrict__ in_idx,
    const int* __restrict__ mask,
    float* __restrict__ out)
{
    __shared__ bf16x8 ldsB[STG0 * 256];   // 57,344 B

    const int tid  = threadIdx.x;
    const int lane = tid & 63;
    const int wv   = tid >> 6;
    const int col  = lane & 15;
    const int quad = lane >> 4;

    const int m0 = blockIdx.x * VOX_PER_BLK + wv * 16;
    const bool active = (m0 < M_VOX);   // M_VOX%16==0: waves all-or-nothing

    // stage offsets 0..13 into LDS (all waves participate — barrier safety)
#pragma unroll
    for (int i = tid; i < STG0 * 256; i += BLK_THREADS) ldsB[i] = BfragG[i];

    // full index chain up front: 54 coalesced loads, mask fused -> zero row
    int mi[K_VOL];
    if (active) {
#pragma unroll
        for (int k = 0; k < K_VOL; ++k) {
            const int ix = in_idx[k * M_VOX + m0 + col];
            const int mk = mask[k * M_VOX + m0 + col];
            mi[k] = mk ? ix : N_VOX;
        }
    }
    __syncthreads();   // LDS stage 0 ready

    floatx4 acc0 = {0.f,0.f,0.f,0.f}, acc1 = {0.f,0.f,0.f,0.f};
    floatx4 acc2 = {0.f,0.f,0.f,0.f}, acc3 = {0.f,0.f,0.f,0.f};
    const bf16x8* lbase = ldsB + lane;
    const __bf16* fbase = featsB + quad * 8;

    bf16x8 A[BURST];

    if (active) {
        // ---- stage 0, batch 0: offsets 0..6 ----
#pragma unroll
        for (int j = 0; j < BURST; ++j)
            A[j] = *(const bf16x8*)(fbase + (size_t)mi[j] * C_IN);
#pragma unroll
        for (int j = 0; j < BURST; ++j) {
            const int k = j;
            bf16x8 b0 = lbase[k * 256 + 0 * 64];
            bf16x8 b1 = lbase[k * 256 + 1 * 64];
            bf16x8 b2 = lbase[k * 256 + 2 * 64];
            bf16x8 b3 = lbase[k * 256 + 3 * 64];
            acc0 = __builtin_amdgcn_mfma_f32_16x16x32_bf16(A[j], b0, acc0, 0, 0, 0);
            acc1 = __builtin_amdgcn_mfma_f32_16x16x32_bf16(A[j], b1, acc1, 0, 0, 0);
            acc2 = __builtin_amdgcn_mfma_f32_16x16x32_bf16(A[j], b2, acc2, 0, 0, 0);
            acc3 = __builtin_amdgcn_mfma_f32_16x16x32_bf16(A[j], b3, acc3, 0, 0, 0);
        }
        // ---- stage 0, batch 1: offsets 7..13 ----
#pragma unroll
        for (int j = 0; j < BURST; ++j)
            A[j] = *(const bf16x8*)(fbase + (size_t)mi[BURST + j] * C_IN);
#pragma unroll
        for (int j = 0; j < BURST; ++j) {
            const int k = BURST + j;
            bf16x8 b0 = lbase[k * 256 + 0 * 64];
            bf16x8 b1 = lbase[k * 256 + 1 * 64];
            bf16x8 b2 = lbase[k * 256 + 2 * 64];
            bf16x8 b3 = lbase[k * 256 + 3 * 64];
            acc0 = __builtin_amdgcn_mfma_f32_16x16x32_bf16(A[j], b0, acc0, 0, 0, 0);
            acc1 = __builtin_amdgcn_mfma_f32_16x16x32_bf16(A[j], b1, acc1, 0, 0, 0);
            acc2 = __builtin_amdgcn_mfma_f32_16x16x32_bf16(A[j], b2, acc2, 0, 0, 0);
            acc3 = __builtin_amdgcn_mfma_f32_16x16x32_bf16(A[j], b3, acc3, 0, 0, 0);
        }
    }

    // ---- restage LDS with offsets 14..26 ----
    __syncthreads();   // everyone done reading LDS stage 0
#pragma unroll
    for (int i = tid; i < STG1 * 256; i += BLK_THREADS)
        ldsB[i] = BfragG[STG0 * 256 + i];
    __syncthreads();   // LDS stage 1 ready

    if (active) {
        // ---- stage 1, batch 0: offsets 14..20 ----
#pragma unroll
        for (int j = 0; j < BURST; ++j)
            A[j] = *(const bf16x8*)(fbase + (size_t)mi[STG0 + j] * C_IN);
#pragma unroll
        for (int j = 0; j < BURST; ++j) {
            const int k = j;
            bf16x8 b0 = lbase[k * 256 + 0 * 64];
            bf16x8 b1 = lbase[k * 256 + 1 * 64];
            bf16x8 b2 = lbase[k * 256 + 2 * 64];
            bf16x8 b3 = lbase[k * 256 + 3 * 64];
            acc0 = __builtin_amdgcn_mfma_f32_16x16x32_bf16(A[j], b0, acc0, 0, 0, 0);
            acc1 = __builtin_amdgcn_mfma_f32_16x16x32_bf16(A[j], b1, acc1, 0, 0, 0);
            acc2 = __builtin_amdgcn_mfma_f32_16x16x32_bf16(A[j], b2, acc2, 0, 0, 0);
            acc3 = __builtin_amdgcn_mfma_f32_16x16x32_bf16(A[j], b3, acc3, 0, 0, 0);
        }
        // ---- stage 1, batch 1: offsets 21..26 (6 iters) ----
#pragma unroll
        for (int j = 0; j < STG1 - BURST; ++j)
            A[j] = *(const bf16x8*)(fbase + (size_t)mi[STG0 + BURST + j] * C_IN);
#pragma unroll
        for (int j = 0; j < STG1 - BURST; ++j) {
            const int k = BURST + j;
            bf16x8 b0 = lbase[k * 256 + 0 * 64];
            bf16x8 b1 = lbase[k * 256 + 1 * 64];
            bf16x8 b2 = lbase[k * 256 + 2 * 64];
            bf16x8 b3 = lbase[k * 256 + 3 * 64];
            acc0 = __builtin_amdgcn_mfma_f32_16x16x32_bf16(A[j], b0, acc0, 0, 0, 0);
            acc1 = __builtin_amdgcn_mfma_f32_16x16x32_bf16(A[j], b1, acc1, 0, 0, 0);
            acc2 = __builtin_amdgcn_mfma_f32_16x16x32_bf16(A[j], b2, acc2, 0, 0, 0);
            acc3 = __builtin_amdgcn_mfma_f32_16x16x32_bf16(A[j], b3, acc3, 0, 0, 0);
        }

        float* op = out + (size_t)(m0 + quad * 4) * C_OUT + col;
#pragma unroll
        for (int r = 0; r < 4; ++r) {
            op[r * C_OUT + 0]  = acc0[r];
            op[r * C_OUT + 16] = acc1[r];
            op[r * C_OUT + 32] = acc2[r];
            op[r * C_OUT + 48] = acc3[r];
        }
    }
}

extern "C" void kernel_launch(void* const* d_in, const int* in_sizes, int n_in,
                              void* d_out, int out_size, void* d_ws, size_t ws_size,
                              hipStream_t stream) {
    const float* feats   = (const float*)d_in[0];
    const float* kernelw = (const float*)d_in[1];
    const int*   in_idx  = (const int*)d_in[2];
    const int*   maskp   = (const int*)d_in[3];
    float*       out     = (float*)d_out;

    __bf16* featsB = (__bf16*)d_ws;
    bf16x8* BfragP = (bf16x8*)((char*)d_ws + BFRAG_OFF);

    prep_all<<<dim3(FEAT_BLOCKS + K_VOL), dim3(256), 0, stream>>>(
        feats, kernelw, featsB, BfragP);

    const int blocks = (M_VOX + VOX_PER_BLK - 1) / VOX_PER_BLK;   // 782
    sparse_conv_mfma<<<dim3(blocks), dim3(BLK_THREADS), 0, stream>>>(
        featsB, BfragP, in_idx, maskp, out);
}